// Round 12
// baseline (310.798 us; speedup 1.0000x reference)
//
#include <hip/hip_runtime.h>
#include <hip/hip_bf16.h>

#define NSEG 200
#define STRENGTH 1e-3f
#define NFB 8192                  // fine bins per segment
#define FSCALE (8192.0f / 12.0f)
#define BT 1024                   // threads per segment block
#define CHUNK 6144                // slots per phase-3 window chunk
#define WINCAP 6656               // CHUNK + margin for partial edge bins

__device__ __forceinline__ int fbin_of(float v) {
    float t = (v + 6.0f) * FSCALE;
    int b = (int)floorf(t);
    return b < 0 ? 0 : (b > NFB - 1 ? NFB - 1 : b);
}

// ---- 0. segment boundaries from sorted seg ids ----
__global__ void k_bounds(const int* __restrict__ seg, int* __restrict__ seg_starts, int N) {
    int stride = gridDim.x * blockDim.x;
    int tid = blockIdx.x * blockDim.x + threadIdx.x;
    if (tid == 0) { seg_starts[0] = 0; seg_starts[NSEG] = N; }
    const int4* s4 = (const int4*)seg;
    int N4 = N >> 2;
    for (int i = tid; i < N4; i += stride) {
        int4 s = s4[i];
        int prev = (i == 0) ? s.x : seg[i * 4 - 1];
        if (s.x != prev) seg_starts[s.x] = i * 4;
        if (s.y != s.x) seg_starts[s.y] = i * 4 + 1;
        if (s.z != s.y) seg_starts[s.z] = i * 4 + 2;
        if (s.w != s.z) seg_starts[s.w] = i * 4 + 3;
    }
}

// ---- 1. fused per-segment kernel: hist -> prefix -> scatter -> rank+diff ----
__global__ void __launch_bounds__(BT)
k_seg(const float* __restrict__ x, const float* __restrict__ y,
      const int* __restrict__ seg_starts, float* __restrict__ sx,
      float* __restrict__ segSums) {
    __shared__ unsigned fw[NFB];                       // 32 KB: counts -> prefix -> cursors -> P[f+1]
    __shared__ __align__(16) float win[WINCAP + 4];    // 26 KB: staged window
    __shared__ int shw[2];
    __shared__ unsigned wsum[16];
    __shared__ float warr[16];

    int s = blockIdx.x;
    int t = threadIdx.x;
    int st = seg_starts[s], en = seg_starts[s + 1];
    int n = en - st;
    if (n <= 0) { if (t == 0) segSums[s] = 0.f; return; }
    const float* xs = x + st;
    float* sxs = sx + st;
    const float* ys = y + st;

    // ---- phase 1: fine histogram ----
    for (int k = t; k < NFB; k += BT) fw[k] = 0;
    __syncthreads();
    for (int k = t; k < n; k += BT) atomicAdd(&fw[fbin_of(xs[k])], 1u);
    __syncthreads();

    // ---- prefix: 8 bins/thread + wave shfl scan + one LDS exchange ----
    unsigned wbuf[8]; unsigned run = 0;
    #pragma unroll
    for (int i = 0; i < 8; ++i) { unsigned c = fw[t * 8 + i]; wbuf[i] = run; run += c; }
    unsigned incl = run;
    for (int off = 1; off < 64; off <<= 1) {
        unsigned nv = __shfl_up(incl, off, 64);
        if ((t & 63) >= off) incl += nv;
    }
    if ((t & 63) == 63) wsum[t >> 6] = incl;
    __syncthreads();
    unsigned wbase = 0;
    int myw = t >> 6;
    #pragma unroll
    for (int j = 0; j < 16; ++j) wbase += (j < myw) ? wsum[j] : 0u;
    unsigned base = wbase + incl - run;
    #pragma unroll
    for (int i = 0; i < 8; ++i) fw[t * 8 + i] = base + wbuf[i];
    __syncthreads();

    // ---- phase 2: scatter values to global sxs; fw becomes P[f+1] ----
    for (int k = t; k < n; k += BT) {
        float v = xs[k];
        unsigned slot = atomicAdd(&fw[fbin_of(v)], 1u);
        sxs[slot] = v;
    }
    __threadfence();
    __syncthreads();
    // now: fstart(f) = f ? fw[f-1] : 0 ; fend(f) = fw[f] (f==NFB-1 -> n)

    // ---- phase 3: chunked windows, rank within fine bin + |diff| ----
    float acc = 0.f;
    int nch = (n + CHUNK - 1) / CHUNK;
    for (int c = 0; c < nch; ++c) {
        int c0 = c * CHUNK;
        int c1 = min(c0 + CHUNK, n);
        if (t == 0) {
            int f0 = fbin_of(sxs[c0]);
            shw[0] = f0 ? (int)fw[f0 - 1] : 0;
            int f1 = fbin_of(sxs[c1 - 1]);
            shw[1] = (int)fw[f1];
        }
        __syncthreads();
        int w0 = shw[0], w1 = shw[1];
        int wsz = w1 - w0;
        bool staged = wsz <= WINCAP;     // block-uniform
        if (staged) {
            for (int k = t; k < wsz; k += BT) win[k] = sxs[w0 + k];
            if (t < 4) win[wsz + t] = __builtin_inff();   // pad for float4 over-read
        }
        __syncthreads();
        for (int q = c0 + t; q < c1; q += BT) {
            float v = staged ? win[q - w0] : sxs[q];
            int f = fbin_of(v);
            int fs = f ? (int)fw[f - 1] : 0;
            int fe = (int)fw[f];
            int rank;
            if (staged) {
                // fine bins are value-monotone within the segment: under-read
                // [a,fsl) hits strictly-smaller values (cancelled), over-read
                // past fel hits strictly-larger values / INF pad (adds 0).
                int fsl = fs - w0, fel = fe - w0;
                int a = fsl & ~3;
                int cnt = 0;
                for (int j = a; j < fel; j += 4) {
                    float4 qv = *(const float4*)&win[j];
                    int jg = w0 + j;
                    cnt += (qv.x < v) + ((qv.x == v) & (jg + 0 < q));
                    cnt += (qv.y < v) + ((qv.y == v) & (jg + 1 < q));
                    cnt += (qv.z < v) + ((qv.z == v) & (jg + 2 < q));
                    cnt += (qv.w < v) + ((qv.w == v) & (jg + 3 < q));
                }
                rank = fs + cnt - (fsl - a);
            } else {
                // oversized window (pathological bin): exact global scan
                int cnt = 0;
                for (int j = fs; j < fe; ++j) {
                    float u = sxs[j];
                    cnt += (u < v) + ((u == v) & (j < q));
                }
                rank = fs + cnt;
            }
            acc += fabsf(v - ys[rank]);
        }
        __syncthreads();
    }

    // ---- block reduce -> segSums[s] = sum / n ----
    for (int off = 32; off > 0; off >>= 1) acc += __shfl_xor(acc, off, 64);
    if ((t & 63) == 0) warr[t >> 6] = acc;
    __syncthreads();
    if (t == 0) {
        float tot = 0.f;
        #pragma unroll
        for (int j = 0; j < 16; ++j) tot += warr[j];
        segSums[s] = tot / (float)n;
    }
}

// ---- 2. finalize: mean over segments * strength ----
__global__ void k_final(const float* __restrict__ segSums, float* __restrict__ out) {
    __shared__ float red[256];
    int t = threadIdx.x;
    float a = 0.f;
    for (int k = t; k < NSEG; k += 256) a += segSums[k];
    red[t] = a;
    __syncthreads();
    for (int off = 128; off > 0; off >>= 1) {
        if (t < off) red[t] += red[t + off];
        __syncthreads();
    }
    if (t == 0) out[0] = red[0] * (1.0f / (float)NSEG) * STRENGTH;
}

extern "C" void kernel_launch(void* const* d_in, const int* in_sizes, int n_in,
                              void* d_out, int out_size, void* d_ws, size_t ws_size,
                              hipStream_t stream) {
    const float* x = (const float*)d_in[0];
    const float* y = (const float*)d_in[1];          // initial_sorted
    const int* seg = (const int*)d_in[2];            // segment_ids (sorted)
    int N = in_sizes[0];

    char* ws = (char*)d_ws;
    float* sx        = (float*)ws;                    // N floats
    float* segSums   = (float*)(ws + (size_t)N * 4);  // NSEG floats
    int*   seg_starts= (int*)(segSums + NSEG);        // NSEG+1 ints

    k_bounds<<<512, 256, 0, stream>>>(seg, seg_starts, N);
    k_seg<<<NSEG, BT, 0, stream>>>(x, y, seg_starts, sx, segSums);
    k_final<<<1, 256, 0, stream>>>(segSums, (float*)d_out);
}

// Round 13
// 149.163 us; speedup vs baseline: 2.0836x; 2.0836x over previous
//
#include <hip/hip_runtime.h>
#include <hip/hip_bf16.h>

#define NSEG 200
#define STRENGTH 1e-3f
#define NFB 8192                    // fine bins per segment
#define FSCALE (8192.0f / 12.0f)
#define BT 1024                     // threads per block
#define SPLIT 2                     // blocks per segment
#define CH 9472                     // nominal slots per window
#define WINCAP 9728                 // CH + max bin (<=256)

__device__ __forceinline__ int fbin_of(float v) {
    float t = (v + 6.0f) * FSCALE;
    int b = (int)floorf(t);
    return b < 0 ? 0 : (b > NFB - 1 ? NFB - 1 : b);
}

// ---- 0. segment boundaries from sorted seg ids + zero segSums ----
__global__ void k_bounds(const int* __restrict__ seg, int* __restrict__ seg_starts,
                         float* __restrict__ segSums, int N) {
    int stride = gridDim.x * blockDim.x;
    int tid = blockIdx.x * blockDim.x + threadIdx.x;
    if (tid == 0) { seg_starts[0] = 0; seg_starts[NSEG] = N; }
    for (int k = tid; k < NSEG; k += stride) segSums[k] = 0.f;
    const int4* s4 = (const int4*)seg;
    int N4 = N >> 2;
    for (int i = tid; i < N4; i += stride) {
        int4 s = s4[i];
        int prev = (i == 0) ? s.x : seg[i * 4 - 1];
        if (s.x != prev) seg_starts[s.x] = i * 4;
        if (s.y != s.x) seg_starts[s.y] = i * 4 + 1;
        if (s.z != s.y) seg_starts[s.z] = i * 4 + 2;
        if (s.w != s.z) seg_starts[s.w] = i * 4 + 3;
    }
}

// ---- 1. fused per-segment: hist -> u16 prefix -> LDS-staged windows -> rank+diff ----
// No global scatter: windows are built in LDS from L2-resident re-scans of x.
__global__ void __launch_bounds__(BT)
k_seg(const float* __restrict__ x, const float* __restrict__ y,
      const int* __restrict__ seg_starts, float* __restrict__ segSums) {
    __shared__ unsigned short pfx[NFB + 2];            // 16388 B: exclusive prefix, pfx[NFB]=n
    __shared__ unsigned cur[NFB / 4];                  // 8192 B: packed byte cursors
    __shared__ __align__(16) float win[WINCAP + 4];    // 38928 B: staged window (+INF pad)
    __shared__ int B[12];                              // window bin boundaries
    __shared__ unsigned wsum[16];
    __shared__ float warr[16];
    unsigned* h32 = (unsigned*)win;                    // phase-1 overlay (32 KB <= win)

    int s = blockIdx.x / SPLIT;
    int half = blockIdx.x % SPLIT;
    int t = threadIdx.x;
    int st = seg_starts[s], en = seg_starts[s + 1];
    int n = en - st;
    if (n <= 0) return;
    const float* xs = x + st;
    const float* ys = y + st;

    // ---- phase 1: fine histogram (h32 overlays win) ----
    for (int k = t; k < NFB; k += BT) h32[k] = 0;
    __syncthreads();
    for (int k = t; k < n; k += BT) atomicAdd(&h32[fbin_of(xs[k])], 1u);
    __syncthreads();

    // ---- exclusive prefix -> u16 pfx (8 bins/thread + wave scan + LDS exchange) ----
    unsigned wbuf[8]; unsigned run = 0;
    #pragma unroll
    for (int i = 0; i < 8; ++i) { unsigned c = h32[t * 8 + i]; wbuf[i] = run; run += c; }
    unsigned incl = run;
    for (int off = 1; off < 64; off <<= 1) {
        unsigned nv = __shfl_up(incl, off, 64);
        if ((t & 63) >= off) incl += nv;
    }
    if ((t & 63) == 63) wsum[t >> 6] = incl;
    __syncthreads();
    unsigned wb = 0; int myw = t >> 6;
    #pragma unroll
    for (int j = 0; j < 16; ++j) wb += (j < myw) ? wsum[j] : 0u;
    unsigned base = wb + incl - run;
    #pragma unroll
    for (int i = 0; i < 8; ++i) pfx[t * 8 + i] = (unsigned short)(base + wbuf[i]);
    if (t == BT - 1) pfx[NFB] = (unsigned short)(base + run);    // = n
    __syncthreads();

    // ---- window bin boundaries via binary search over pfx ----
    int nch = (n + CH - 1) / CH;
    if (t == 0) { B[0] = 0; B[nch] = NFB; }
    if (t >= 1 && t < nch) {
        int target = t * CH;
        int lo = 0, hi = NFB - 1;
        while (lo < hi) { int mid = (lo + hi) >> 1; if ((int)pfx[mid + 1] > target) hi = mid; else lo = mid + 1; }
        B[t] = lo;
    }
    __syncthreads();

    // ---- phases 2+3 per assigned window: LDS stage + rank + diff ----
    float acc = 0.f;
    for (int c = half; c < nch; c += SPLIT) {
        int Fa = B[c], Fb = B[c + 1];
        int w0 = (int)pfx[Fa], w1 = (int)pfx[Fb];
        int wsz = w1 - w0;                       // <= CH + maxbin <= WINCAP
        for (int k = t; k < NFB / 4; k += BT) cur[k] = 0;
        __syncthreads();
        // stage: re-scan segment, keep elements whose bin lies in [Fa, Fb)
        for (int k = t; k < n; k += BT) {
            float v = xs[k];
            int f = fbin_of(v);
            if (f >= Fa && f < Fb) {
                unsigned shf = (f & 3) * 8;
                unsigned old = atomicAdd(&cur[f >> 2], 1u << shf);
                int slot = (int)pfx[f] - w0 + (int)((old >> shf) & 0xFFu);
                win[slot] = v;
            }
        }
        if (t < 4) win[wsz + t] = __builtin_inff();   // pad for float4 over-read
        __syncthreads();
        // rank within fine bin (monotone bins: under-read strictly smaller,
        // over-read strictly larger / INF pad). Ties by staged slot (bijection).
        for (int q = w0 + t; q < w1; q += BT) {
            float v = win[q - w0];
            int f = fbin_of(v);
            int bs = (int)pfx[f], be = (int)pfx[f + 1];
            int ls = bs - w0, le = be - w0;
            int a = ls & ~3;
            int cnt = a - ls;                    // cancels under-read smaller hits
            for (int j = a; j < le; j += 4) {
                float4 qv = *(const float4*)&win[j];
                int jg = w0 + j;
                cnt += (qv.x < v) + ((qv.x == v) & (jg + 0 < q));
                cnt += (qv.y < v) + ((qv.y == v) & (jg + 1 < q));
                cnt += (qv.z < v) + ((qv.z == v) & (jg + 2 < q));
                cnt += (qv.w < v) + ((qv.w == v) & (jg + 3 < q));
            }
            acc += fabsf(v - ys[bs + cnt]);
        }
        __syncthreads();
    }

    // ---- reduce partial sum; two blocks per segment -> atomicAdd ----
    for (int off = 32; off > 0; off >>= 1) acc += __shfl_xor(acc, off, 64);
    if ((t & 63) == 0) warr[t >> 6] = acc;
    __syncthreads();
    if (t == 0) {
        float tot = 0.f;
        #pragma unroll
        for (int j = 0; j < 16; ++j) tot += warr[j];
        if (tot != 0.f) atomicAdd(&segSums[s], tot);
    }
}

// ---- 2. finalize: mean over segments of sum/n * strength ----
__global__ void k_final(const float* __restrict__ segSums, const int* __restrict__ seg_starts,
                        float* __restrict__ out) {
    __shared__ float red[256];
    int t = threadIdx.x;
    float a = 0.f;
    for (int k = t; k < NSEG; k += 256) {
        float n = (float)(seg_starts[k + 1] - seg_starts[k]);
        a += segSums[k] / fmaxf(n, 1.0f);
    }
    red[t] = a;
    __syncthreads();
    for (int off = 128; off > 0; off >>= 1) {
        if (t < off) red[t] += red[t + off];
        __syncthreads();
    }
    if (t == 0) out[0] = red[0] * (1.0f / (float)NSEG) * STRENGTH;
}

extern "C" void kernel_launch(void* const* d_in, const int* in_sizes, int n_in,
                              void* d_out, int out_size, void* d_ws, size_t ws_size,
                              hipStream_t stream) {
    const float* x = (const float*)d_in[0];
    const float* y = (const float*)d_in[1];          // initial_sorted
    const int* seg = (const int*)d_in[2];            // segment_ids (sorted)
    int N = in_sizes[0];

    char* ws = (char*)d_ws;
    float* segSums    = (float*)ws;                   // NSEG floats
    int*   seg_starts = (int*)(segSums + NSEG);       // NSEG+1 ints

    k_bounds<<<512, 256, 0, stream>>>(seg, seg_starts, segSums, N);
    k_seg<<<NSEG * SPLIT, BT, 0, stream>>>(x, y, seg_starts, segSums);
    k_final<<<1, 256, 0, stream>>>(segSums, seg_starts, (float*)d_out);
}

// Round 14
// 128.784 us; speedup vs baseline: 2.4133x; 1.1582x over previous
//
#include <hip/hip_runtime.h>
#include <hip/hip_bf16.h>

#define NSEG 200
#define STRENGTH 1e-3f
#define NFB 8192                    // fine bins per segment
#define FSCALE (8192.0f / 12.0f)
#define BT 1024                     // threads per block
#define SPLIT 4                     // k_seg blocks per segment
#define CH 9472                     // nominal slots per window
#define WINCAP 9728                 // CH + max bin (<=256)
#define PSTRIDE (NFB + 8)           // u16 per segment in global pfx table (16B-aligned)

__device__ __forceinline__ int fbin_of(float v) {
    float t = (v + 6.0f) * FSCALE;
    int b = (int)floorf(t);
    return b < 0 ? 0 : (b > NFB - 1 ? NFB - 1 : b);
}

// ---- 0. segment boundaries from sorted seg ids + zero segSums ----
__global__ void k_bounds(const int* __restrict__ seg, int* __restrict__ seg_starts,
                         float* __restrict__ segSums, int N) {
    int stride = gridDim.x * blockDim.x;
    int tid = blockIdx.x * blockDim.x + threadIdx.x;
    if (tid == 0) { seg_starts[0] = 0; seg_starts[NSEG] = N; }
    for (int k = tid; k < NSEG; k += stride) segSums[k] = 0.f;
    const int4* s4 = (const int4*)seg;
    int N4 = N >> 2;
    for (int i = tid; i < N4; i += stride) {
        int4 s = s4[i];
        int prev = (i == 0) ? s.x : seg[i * 4 - 1];
        if (s.x != prev) seg_starts[s.x] = i * 4;
        if (s.y != s.x) seg_starts[s.y] = i * 4 + 1;
        if (s.z != s.y) seg_starts[s.z] = i * 4 + 2;
        if (s.w != s.z) seg_starts[s.w] = i * 4 + 3;
    }
}

// ---- 1. per-segment fine histogram + exclusive prefix -> global u16 table ----
__global__ void __launch_bounds__(BT)
k_hist(const float* __restrict__ x, const int* __restrict__ seg_starts,
       unsigned short* __restrict__ pfxg) {
    __shared__ unsigned h32[NFB];
    __shared__ unsigned wsum[16];
    int s = blockIdx.x;
    int t = threadIdx.x;
    int st = seg_starts[s], en = seg_starts[s + 1];
    int n = en - st;
    const float* xs = x + st;
    for (int k = t; k < NFB; k += BT) h32[k] = 0;
    __syncthreads();
    if (n > 0) {
        int head = min(n, (4 - (st & 3)) & 3);
        for (int k = t; k < head; k += BT) atomicAdd(&h32[fbin_of(xs[k])], 1u);
        int nv = (n - head) >> 2;
        const float4* xs4 = (const float4*)(xs + head);
        for (int j = t; j < nv; j += BT) {
            float4 v = xs4[j];
            atomicAdd(&h32[fbin_of(v.x)], 1u);
            atomicAdd(&h32[fbin_of(v.y)], 1u);
            atomicAdd(&h32[fbin_of(v.z)], 1u);
            atomicAdd(&h32[fbin_of(v.w)], 1u);
        }
        for (int k = head + nv * 4 + t; k < n; k += BT) atomicAdd(&h32[fbin_of(xs[k])], 1u);
    }
    __syncthreads();
    // exclusive prefix: 8 bins/thread + wave shfl scan + one LDS exchange
    unsigned wbuf[8]; unsigned run = 0;
    #pragma unroll
    for (int i = 0; i < 8; ++i) { unsigned c = h32[t * 8 + i]; wbuf[i] = run; run += c; }
    unsigned incl = run;
    for (int off = 1; off < 64; off <<= 1) {
        unsigned nv2 = __shfl_up(incl, off, 64);
        if ((t & 63) >= off) incl += nv2;
    }
    if ((t & 63) == 63) wsum[t >> 6] = incl;
    __syncthreads();
    unsigned wb = 0; int myw = t >> 6;
    #pragma unroll
    for (int j = 0; j < 16; ++j) wb += (j < myw) ? wsum[j] : 0u;
    unsigned base = wb + incl - run;
    unsigned short* pp = pfxg + (size_t)s * PSTRIDE;
    unsigned pk0 = (base + wbuf[0]) | ((base + wbuf[1]) << 16);
    unsigned pk1 = (base + wbuf[2]) | ((base + wbuf[3]) << 16);
    unsigned pk2 = (base + wbuf[4]) | ((base + wbuf[5]) << 16);
    unsigned pk3 = (base + wbuf[6]) | ((base + wbuf[7]) << 16);
    ((uint4*)pp)[t] = make_uint4(pk0, pk1, pk2, pk3);
    if (t == BT - 1) pp[NFB] = (unsigned short)(base + run);   // = n
}

// ---- 2. per-(segment,quarter): LDS-staged windows -> rank+diff ----
__global__ void __launch_bounds__(BT)
k_seg(const float* __restrict__ x, const float* __restrict__ y,
      const int* __restrict__ seg_starts, const unsigned short* __restrict__ pfxg,
      float* __restrict__ segSums) {
    __shared__ unsigned short pfx[NFB + 2];            // 16388 B
    __shared__ unsigned cur[NFB / 4];                  // 8192 B packed byte cursors
    __shared__ __align__(16) float win[WINCAP + 4];    // 38928 B
    __shared__ int B[12];
    __shared__ float warr[16];

    int s = blockIdx.x / SPLIT;
    int half = blockIdx.x % SPLIT;
    int t = threadIdx.x;
    int st = seg_starts[s], en = seg_starts[s + 1];
    int n = en - st;
    if (n <= 0) return;
    const float* xs = x + st;
    const float* ys = y + st;

    // load prefix table (coalesced 16B)
    const unsigned short* pp = pfxg + (size_t)s * PSTRIDE;
    ((uint4*)pfx)[t] = ((const uint4*)pp)[t];
    if (t == 0) pfx[NFB] = pp[NFB];
    __syncthreads();

    // window bin boundaries
    int nch = (n + CH - 1) / CH;
    if (t == 0) { B[0] = 0; B[nch] = NFB; }
    if (t >= 1 && t < nch) {
        int target = t * CH;
        int lo = 0, hi = NFB - 1;
        while (lo < hi) { int mid = (lo + hi) >> 1; if ((int)pfx[mid + 1] > target) hi = mid; else lo = mid + 1; }
        B[t] = lo;
    }
    __syncthreads();

    int head = min(n, (4 - (st & 3)) & 3);
    int nv = (n - head) >> 2;
    const float4* xs4 = (const float4*)(xs + head);
    int tail0 = head + nv * 4;

    float acc = 0.f;
    for (int c = half; c < nch; c += SPLIT) {
        int Fa = B[c], Fb = B[c + 1];
        int w0 = (int)pfx[Fa], w1 = (int)pfx[Fb];
        int wsz = w1 - w0;
        int wA = Fa >> 2, wB = ((Fb - 1) >> 2) + 1;
        for (int k = wA + t; k < wB; k += BT) cur[k] = 0;
        __syncthreads();
        // stage: float4 re-scan of segment, keep bins in [Fa, Fb)
        for (int k = t; k < head; k += BT) {
            float v = xs[k];
            int f = fbin_of(v);
            if (f >= Fa && f < Fb) {
                unsigned shf = (f & 3) * 8;
                unsigned old = atomicAdd(&cur[f >> 2], 1u << shf);
                win[(int)pfx[f] - w0 + (int)((old >> shf) & 0xFFu)] = v;
            }
        }
        for (int j = t; j < nv; j += BT) {
            float4 v4 = xs4[j];
            #pragma unroll
            for (int e = 0; e < 4; ++e) {
                float v = (e == 0) ? v4.x : (e == 1) ? v4.y : (e == 2) ? v4.z : v4.w;
                int f = fbin_of(v);
                if (f >= Fa && f < Fb) {
                    unsigned shf = (f & 3) * 8;
                    unsigned old = atomicAdd(&cur[f >> 2], 1u << shf);
                    win[(int)pfx[f] - w0 + (int)((old >> shf) & 0xFFu)] = v;
                }
            }
        }
        for (int k = tail0 + t; k < n; k += BT) {
            float v = xs[k];
            int f = fbin_of(v);
            if (f >= Fa && f < Fb) {
                unsigned shf = (f & 3) * 8;
                unsigned old = atomicAdd(&cur[f >> 2], 1u << shf);
                win[(int)pfx[f] - w0 + (int)((old >> shf) & 0xFFu)] = v;
            }
        }
        if (t < 4) win[wsz + t] = __builtin_inff();   // pad for float4 over-read
        __syncthreads();
        // rank within fine bin (monotone bins: under-read strictly smaller ->
        // cancelled; over-read strictly larger / INF pad -> adds 0).
        for (int q = w0 + t; q < w1; q += BT) {
            float v = win[q - w0];
            int f = fbin_of(v);
            int bs = (int)pfx[f], be = (int)pfx[f + 1];
            int ls = bs - w0, le = be - w0;
            int a = ls & ~3;
            int cnt = a - ls;
            for (int j = a; j < le; j += 4) {
                float4 qv = *(const float4*)&win[j];
                int jg = w0 + j;
                cnt += (qv.x < v) + ((qv.x == v) & (jg + 0 < q));
                cnt += (qv.y < v) + ((qv.y == v) & (jg + 1 < q));
                cnt += (qv.z < v) + ((qv.z == v) & (jg + 2 < q));
                cnt += (qv.w < v) + ((qv.w == v) & (jg + 3 < q));
            }
            acc += fabsf(v - ys[bs + cnt]);
        }
        __syncthreads();
    }

    for (int off = 32; off > 0; off >>= 1) acc += __shfl_xor(acc, off, 64);
    if ((t & 63) == 0) warr[t >> 6] = acc;
    __syncthreads();
    if (t == 0) {
        float tot = 0.f;
        #pragma unroll
        for (int j = 0; j < 16; ++j) tot += warr[j];
        if (tot != 0.f) atomicAdd(&segSums[s], tot);
    }
}

// ---- 3. finalize: mean over segments of sum/n * strength ----
__global__ void k_final(const float* __restrict__ segSums, const int* __restrict__ seg_starts,
                        float* __restrict__ out) {
    __shared__ float red[256];
    int t = threadIdx.x;
    float a = 0.f;
    for (int k = t; k < NSEG; k += 256) {
        float n = (float)(seg_starts[k + 1] - seg_starts[k]);
        a += segSums[k] / fmaxf(n, 1.0f);
    }
    red[t] = a;
    __syncthreads();
    for (int off = 128; off > 0; off >>= 1) {
        if (t < off) red[t] += red[t + off];
        __syncthreads();
    }
    if (t == 0) out[0] = red[0] * (1.0f / (float)NSEG) * STRENGTH;
}

extern "C" void kernel_launch(void* const* d_in, const int* in_sizes, int n_in,
                              void* d_out, int out_size, void* d_ws, size_t ws_size,
                              hipStream_t stream) {
    const float* x = (const float*)d_in[0];
    const float* y = (const float*)d_in[1];          // initial_sorted
    const int* seg = (const int*)d_in[2];            // segment_ids (sorted)
    int N = in_sizes[0];

    char* ws = (char*)d_ws;
    float* segSums    = (float*)ws;                               // NSEG floats
    int*   seg_starts = (int*)(segSums + NSEG);                   // NSEG+1 ints
    unsigned short* pfxg = (unsigned short*)(seg_starts + NSEG + 8); // NSEG*PSTRIDE u16

    k_bounds<<<512, 256, 0, stream>>>(seg, seg_starts, segSums, N);
    k_hist<<<NSEG, BT, 0, stream>>>(x, seg_starts, pfxg);
    k_seg<<<NSEG * SPLIT, BT, 0, stream>>>(x, y, seg_starts, pfxg, segSums);
    k_final<<<1, 256, 0, stream>>>(segSums, seg_starts, (float*)d_out);
}

// Round 15
// 104.316 us; speedup vs baseline: 2.9794x; 1.2346x over previous
//
#include <hip/hip_runtime.h>
#include <hip/hip_bf16.h>

#define NSEG 200
#define STRENGTH 1e-3f
#define NFB 8192                    // fine bins per segment
#define FSCALE (8192.0f / 12.0f)
#define BT 1024                     // threads per block
#define SPLIT 5                     // k_seg blocks per segment (~= windows/segment)
#define CH 9472                     // nominal slots per window
#define WINCAP 9728                 // CH + max bin (<=256)
#define PSTRIDE (NFB + 8)           // u16 per segment in global pfx table (16B-aligned)

__device__ __forceinline__ int fbin_of(float v) {
    float t = (v + 6.0f) * FSCALE;
    int b = (int)floorf(t);
    return b < 0 ? 0 : (b > NFB - 1 ? NFB - 1 : b);
}

// ---- 0. segment boundaries from sorted seg ids + zero segSums ----
__global__ void k_bounds(const int* __restrict__ seg, int* __restrict__ seg_starts,
                         float* __restrict__ segSums, int N) {
    int stride = gridDim.x * blockDim.x;
    int tid = blockIdx.x * blockDim.x + threadIdx.x;
    if (tid == 0) { seg_starts[0] = 0; seg_starts[NSEG] = N; }
    for (int k = tid; k < NSEG; k += stride) segSums[k] = 0.f;
    const int4* s4 = (const int4*)seg;
    int N4 = N >> 2;
    for (int i = tid; i < N4; i += stride) {
        int4 s = s4[i];
        int prev = (i == 0) ? s.x : seg[i * 4 - 1];
        if (s.x != prev) seg_starts[s.x] = i * 4;
        if (s.y != s.x) seg_starts[s.y] = i * 4 + 1;
        if (s.z != s.y) seg_starts[s.z] = i * 4 + 2;
        if (s.w != s.z) seg_starts[s.w] = i * 4 + 3;
    }
}

// ---- 1. per-segment fine histogram + exclusive prefix -> global u16 table ----
__global__ void __launch_bounds__(BT)
k_hist(const float* __restrict__ x, const int* __restrict__ seg_starts,
       unsigned short* __restrict__ pfxg) {
    __shared__ unsigned h32[NFB];
    __shared__ unsigned wsum[16];
    int s = blockIdx.x;
    int t = threadIdx.x;
    int st = seg_starts[s], en = seg_starts[s + 1];
    int n = en - st;
    const float* xs = x + st;
    for (int k = t; k < NFB; k += BT) h32[k] = 0;
    __syncthreads();
    if (n > 0) {
        int head = min(n, (4 - (st & 3)) & 3);
        for (int k = t; k < head; k += BT) atomicAdd(&h32[fbin_of(xs[k])], 1u);
        int nv = (n - head) >> 2;
        const float4* xs4 = (const float4*)(xs + head);
        for (int j = t; j < nv; j += BT) {
            float4 v = xs4[j];
            atomicAdd(&h32[fbin_of(v.x)], 1u);
            atomicAdd(&h32[fbin_of(v.y)], 1u);
            atomicAdd(&h32[fbin_of(v.z)], 1u);
            atomicAdd(&h32[fbin_of(v.w)], 1u);
        }
        for (int k = head + nv * 4 + t; k < n; k += BT) atomicAdd(&h32[fbin_of(xs[k])], 1u);
    }
    __syncthreads();
    // exclusive prefix: 8 bins/thread + wave shfl scan + one LDS exchange
    unsigned wbuf[8]; unsigned run = 0;
    #pragma unroll
    for (int i = 0; i < 8; ++i) { unsigned c = h32[t * 8 + i]; wbuf[i] = run; run += c; }
    unsigned incl = run;
    for (int off = 1; off < 64; off <<= 1) {
        unsigned nv2 = __shfl_up(incl, off, 64);
        if ((t & 63) >= off) incl += nv2;
    }
    if ((t & 63) == 63) wsum[t >> 6] = incl;
    __syncthreads();
    unsigned wb = 0; int myw = t >> 6;
    #pragma unroll
    for (int j = 0; j < 16; ++j) wb += (j < myw) ? wsum[j] : 0u;
    unsigned base = wb + incl - run;
    unsigned short* pp = pfxg + (size_t)s * PSTRIDE;
    unsigned pk0 = (base + wbuf[0]) | ((base + wbuf[1]) << 16);
    unsigned pk1 = (base + wbuf[2]) | ((base + wbuf[3]) << 16);
    unsigned pk2 = (base + wbuf[4]) | ((base + wbuf[5]) << 16);
    unsigned pk3 = (base + wbuf[6]) | ((base + wbuf[7]) << 16);
    ((uint4*)pp)[t] = make_uint4(pk0, pk1, pk2, pk3);
    if (t == BT - 1) pp[NFB] = (unsigned short)(base + run);   // = n
}

// ---- 2. per-(segment,window): LDS-staged window -> rank+diff ----
// blockIdx mapping: s = bid % NSEG, half = bid / NSEG. NSEG % 8 == 0, so all
// SPLIT blocks of a segment share bid%8 -> same XCD -> segment x/y stay in
// that XCD's private L2 across the window re-scans.
__global__ void __launch_bounds__(BT)
k_seg(const float* __restrict__ x, const float* __restrict__ y,
      const int* __restrict__ seg_starts, const unsigned short* __restrict__ pfxg,
      float* __restrict__ segSums) {
    __shared__ unsigned short pfx[NFB + 2];            // 16388 B
    __shared__ unsigned cur[NFB / 4];                  // 8192 B packed byte cursors
    __shared__ __align__(16) float win[WINCAP + 4];    // 38928 B
    __shared__ int B[12];
    __shared__ float warr[16];

    int s = blockIdx.x % NSEG;
    int half = blockIdx.x / NSEG;
    int t = threadIdx.x;
    int st = seg_starts[s], en = seg_starts[s + 1];
    int n = en - st;
    if (n <= 0) return;
    const float* xs = x + st;
    const float* ys = y + st;

    // load prefix table (coalesced 16B)
    const unsigned short* pp = pfxg + (size_t)s * PSTRIDE;
    ((uint4*)pfx)[t] = ((const uint4*)pp)[t];
    if (t == 0) pfx[NFB] = pp[NFB];
    __syncthreads();

    // window bin boundaries
    int nch = (n + CH - 1) / CH;
    if (t == 0) { B[0] = 0; B[nch] = NFB; }
    if (t >= 1 && t < nch) {
        int target = t * CH;
        int lo = 0, hi = NFB - 1;
        while (lo < hi) { int mid = (lo + hi) >> 1; if ((int)pfx[mid + 1] > target) hi = mid; else lo = mid + 1; }
        B[t] = lo;
    }
    __syncthreads();

    int head = min(n, (4 - (st & 3)) & 3);
    int nv = (n - head) >> 2;
    const float4* xs4 = (const float4*)(xs + head);
    int tail0 = head + nv * 4;

    float acc = 0.f;
    for (int c = half; c < nch; c += SPLIT) {
        int Fa = B[c], Fb = B[c + 1];
        int w0 = (int)pfx[Fa], w1 = (int)pfx[Fb];
        int wsz = w1 - w0;
        int wA = Fa >> 2, wB = ((Fb - 1) >> 2) + 1;
        for (int k = wA + t; k < wB; k += BT) cur[k] = 0;
        __syncthreads();
        // stage: float4 re-scan of segment (L2-resident), keep bins in [Fa, Fb)
        for (int k = t; k < head; k += BT) {
            float v = xs[k];
            int f = fbin_of(v);
            if (f >= Fa && f < Fb) {
                unsigned shf = (f & 3) * 8;
                unsigned old = atomicAdd(&cur[f >> 2], 1u << shf);
                win[(int)pfx[f] - w0 + (int)((old >> shf) & 0xFFu)] = v;
            }
        }
        for (int j = t; j < nv; j += BT) {
            float4 v4 = xs4[j];
            #pragma unroll
            for (int e = 0; e < 4; ++e) {
                float v = (e == 0) ? v4.x : (e == 1) ? v4.y : (e == 2) ? v4.z : v4.w;
                int f = fbin_of(v);
                if (f >= Fa && f < Fb) {
                    unsigned shf = (f & 3) * 8;
                    unsigned old = atomicAdd(&cur[f >> 2], 1u << shf);
                    win[(int)pfx[f] - w0 + (int)((old >> shf) & 0xFFu)] = v;
                }
            }
        }
        for (int k = tail0 + t; k < n; k += BT) {
            float v = xs[k];
            int f = fbin_of(v);
            if (f >= Fa && f < Fb) {
                unsigned shf = (f & 3) * 8;
                unsigned old = atomicAdd(&cur[f >> 2], 1u << shf);
                win[(int)pfx[f] - w0 + (int)((old >> shf) & 0xFFu)] = v;
            }
        }
        if (t < 4) win[wsz + t] = __builtin_inff();   // pad for float4 over-read
        __syncthreads();
        // rank within fine bin (monotone bins: under-read strictly smaller ->
        // cancelled; over-read strictly larger / INF pad -> adds 0).
        for (int q = w0 + t; q < w1; q += BT) {
            float v = win[q - w0];
            int f = fbin_of(v);
            int bs = (int)pfx[f], be = (int)pfx[f + 1];
            int ls = bs - w0, le = be - w0;
            int a = ls & ~3;
            int cnt = a - ls;
            for (int j = a; j < le; j += 4) {
                float4 qv = *(const float4*)&win[j];
                int jg = w0 + j;
                cnt += (qv.x < v) + ((qv.x == v) & (jg + 0 < q));
                cnt += (qv.y < v) + ((qv.y == v) & (jg + 1 < q));
                cnt += (qv.z < v) + ((qv.z == v) & (jg + 2 < q));
                cnt += (qv.w < v) + ((qv.w == v) & (jg + 3 < q));
            }
            acc += fabsf(v - ys[bs + cnt]);
        }
        __syncthreads();
    }

    for (int off = 32; off > 0; off >>= 1) acc += __shfl_xor(acc, off, 64);
    if ((t & 63) == 0) warr[t >> 6] = acc;
    __syncthreads();
    if (t == 0) {
        float tot = 0.f;
        #pragma unroll
        for (int j = 0; j < 16; ++j) tot += warr[j];
        if (tot != 0.f) atomicAdd(&segSums[s], tot);
    }
}

// ---- 3. finalize: mean over segments of sum/n * strength ----
__global__ void k_final(const float* __restrict__ segSums, const int* __restrict__ seg_starts,
                        float* __restrict__ out) {
    __shared__ float red[256];
    int t = threadIdx.x;
    float a = 0.f;
    for (int k = t; k < NSEG; k += 256) {
        float n = (float)(seg_starts[k + 1] - seg_starts[k]);
        a += segSums[k] / fmaxf(n, 1.0f);
    }
    red[t] = a;
    __syncthreads();
    for (int off = 128; off > 0; off >>= 1) {
        if (t < off) red[t] += red[t + off];
        __syncthreads();
    }
    if (t == 0) out[0] = red[0] * (1.0f / (float)NSEG) * STRENGTH;
}

extern "C" void kernel_launch(void* const* d_in, const int* in_sizes, int n_in,
                              void* d_out, int out_size, void* d_ws, size_t ws_size,
                              hipStream_t stream) {
    const float* x = (const float*)d_in[0];
    const float* y = (const float*)d_in[1];          // initial_sorted
    const int* seg = (const int*)d_in[2];            // segment_ids (sorted)
    int N = in_sizes[0];

    char* ws = (char*)d_ws;
    float* segSums    = (float*)ws;                               // NSEG floats
    int*   seg_starts = (int*)(segSums + NSEG);                   // NSEG+1 ints
    unsigned short* pfxg = (unsigned short*)(seg_starts + NSEG + 8); // NSEG*PSTRIDE u16

    k_bounds<<<512, 256, 0, stream>>>(seg, seg_starts, segSums, N);
    k_hist<<<NSEG, BT, 0, stream>>>(x, seg_starts, pfxg);
    k_seg<<<NSEG * SPLIT, BT, 0, stream>>>(x, y, seg_starts, pfxg, segSums);
    k_final<<<1, 256, 0, stream>>>(segSums, seg_starts, (float*)d_out);
}

// Round 16
// 102.638 us; speedup vs baseline: 3.0281x; 1.0164x over previous
//
#include <hip/hip_runtime.h>
#include <hip/hip_bf16.h>

#define NSEG 200
#define STRENGTH 1e-3f
#define NFB 8192                    // fine bins per segment
#define FSCALE (8192.0f / 12.0f)
#define BT 1024                     // threads per k_hist/k_seg block
#define SPLIT 5                     // windows (partitions) per segment
#define WINCAP 9728                 // max window slots (n/5 + maxbin + slack)
#define PSTRIDE (NFB + 8)           // u16 per segment in global pfx table
#define PCH 8192                    // elements per k_part chunk

__device__ __forceinline__ int fbin_of(float v) {
    float t = (v + 6.0f) * FSCALE;
    int b = (int)floorf(t);
    return b < 0 ? 0 : (b > NFB - 1 ? NFB - 1 : b);
}

// ---- 0. segment boundaries + zero segSums/gcur ----
__global__ void k_bounds(const int* __restrict__ seg, int* __restrict__ seg_starts,
                         float* __restrict__ segSums, unsigned* __restrict__ gcur, int N) {
    int stride = gridDim.x * blockDim.x;
    int tid = blockIdx.x * blockDim.x + threadIdx.x;
    if (tid == 0) { seg_starts[0] = 0; seg_starts[NSEG] = N; }
    for (int k = tid; k < NSEG; k += stride) segSums[k] = 0.f;
    for (int k = tid; k < NSEG * 8; k += stride) gcur[k] = 0u;
    const int4* s4 = (const int4*)seg;
    int N4 = N >> 2;
    for (int i = tid; i < N4; i += stride) {
        int4 s = s4[i];
        int prev = (i == 0) ? s.x : seg[i * 4 - 1];
        if (s.x != prev) seg_starts[s.x] = i * 4;
        if (s.y != s.x) seg_starts[s.y] = i * 4 + 1;
        if (s.z != s.y) seg_starts[s.z] = i * 4 + 2;
        if (s.w != s.z) seg_starts[s.w] = i * 4 + 3;
    }
}

// ---- 1. per-segment fine hist + prefix -> pfxg; balanced window bounds -> Bg/Bpos ----
__global__ void __launch_bounds__(BT)
k_hist(const float* __restrict__ x, const int* __restrict__ seg_starts,
       unsigned short* __restrict__ pfxg, int* __restrict__ Bg, int* __restrict__ Bpos) {
    __shared__ unsigned h32[NFB];
    __shared__ unsigned wsum[16];
    __shared__ int nsh;
    int s = blockIdx.x;
    int t = threadIdx.x;
    int st = seg_starts[s], en = seg_starts[s + 1];
    int n = en - st;
    const float* xs = x + st;
    for (int k = t; k < NFB; k += BT) h32[k] = 0;
    __syncthreads();
    if (n > 0) {
        int head = min(n, (int)((4 - (st & 3)) & 3));
        for (int k = t; k < head; k += BT) atomicAdd(&h32[fbin_of(xs[k])], 1u);
        int nv = (n - head) >> 2;
        const float4* xs4 = (const float4*)(xs + head);
        for (int j = t; j < nv; j += BT) {
            float4 v = xs4[j];
            atomicAdd(&h32[fbin_of(v.x)], 1u);
            atomicAdd(&h32[fbin_of(v.y)], 1u);
            atomicAdd(&h32[fbin_of(v.z)], 1u);
            atomicAdd(&h32[fbin_of(v.w)], 1u);
        }
        for (int k = head + nv * 4 + t; k < n; k += BT) atomicAdd(&h32[fbin_of(xs[k])], 1u);
    }
    __syncthreads();
    // exclusive prefix: 8 bins/thread + wave shfl scan + one LDS exchange
    unsigned wbuf[8]; unsigned run = 0;
    #pragma unroll
    for (int i = 0; i < 8; ++i) { unsigned c = h32[t * 8 + i]; wbuf[i] = run; run += c; }
    unsigned incl = run;
    for (int off = 1; off < 64; off <<= 1) {
        unsigned nv2 = __shfl_up(incl, off, 64);
        if ((t & 63) >= off) incl += nv2;
    }
    if ((t & 63) == 63) wsum[t >> 6] = incl;
    __syncthreads();
    unsigned wb = 0; int myw = t >> 6;
    #pragma unroll
    for (int j = 0; j < 16; ++j) wb += (j < myw) ? wsum[j] : 0u;
    unsigned pbase = wb + incl - run;
    unsigned short* pp = pfxg + (size_t)s * PSTRIDE;
    unsigned pk0 = (pbase + wbuf[0]) | ((pbase + wbuf[1]) << 16);
    unsigned pk1 = (pbase + wbuf[2]) | ((pbase + wbuf[3]) << 16);
    unsigned pk2 = (pbase + wbuf[4]) | ((pbase + wbuf[5]) << 16);
    unsigned pk3 = (pbase + wbuf[6]) | ((pbase + wbuf[7]) << 16);
    ((uint4*)pp)[t] = make_uint4(pk0, pk1, pk2, pk3);
    if (t == BT - 1) { pp[NFB] = (unsigned short)(pbase + run); nsh = (int)(pbase + run); }
    // overwrite h32 with the exclusive prefix for the quantile search
    #pragma unroll
    for (int i = 0; i < 8; ++i) h32[t * 8 + i] = pbase + wbuf[i];
    __syncthreads();
    if (t == 0) { Bg[s * 8 + 0] = 0; Bg[s * 8 + SPLIT] = NFB; Bpos[s * 8 + 0] = 0; Bpos[s * 8 + SPLIT] = nsh; }
    if (t >= 1 && t < SPLIT) {
        int target = (int)(((long)t * nsh) / SPLIT);
        int lo = 0, hi = NFB - 1;
        while (lo < hi) { int mid = (lo + hi) >> 1; if ((int)h32[mid + 1] > target) hi = mid; else lo = mid + 1; }
        Bg[s * 8 + t] = lo;
        Bpos[s * 8 + t] = (int)h32[lo];
    }
}

// ---- 2. single-pass 5-way partition scatter (block-aggregated, coalesced runs) ----
__global__ void __launch_bounds__(1024)
k_part(const float* __restrict__ x, const int* __restrict__ seg_starts,
       const int* __restrict__ Bg, const int* __restrict__ Bpos,
       unsigned* __restrict__ gcur, float* __restrict__ part, int N) {
    __shared__ int sst[NSEG + 1];
    __shared__ unsigned hh[16][12];     // per-wave replicated (s,p) counters
    __shared__ int gb[10];              // per-sp global write base (absolute)
    __shared__ int sB[8];               // B1..B4 for s0 and s0+1
    int t = threadIdx.x;
    for (int k = t; k < NSEG + 1; k += 1024) sst[k] = seg_starts[k];
    if (t < 192) ((unsigned*)hh)[t] = 0u;
    __syncthreads();
    int base = blockIdx.x * PCH;
    if (base >= N) return;
    int lo = 0, hi = NSEG - 1;
    while (lo < hi) { int mid = (lo + hi) >> 1; if (base < sst[mid + 1]) hi = mid; else lo = mid + 1; }
    int s0 = lo, bnd = sst[s0 + 1];
    if (t < 4) sB[t] = Bg[s0 * 8 + 1 + t];
    else if (t < 8) sB[t] = Bg[(s0 + 1) * 8 + 1 + (t - 4)];
    __syncthreads();
    int grp = t >> 6;
    float vv[8]; unsigned pk[8];
    const float4* x4 = (const float4*)(x + base);
    #pragma unroll
    for (int it = 0; it < 2; ++it) {
        int j = it * 1024 + t;
        int gi = base + j * 4;
        float4 v4;
        if (gi + 3 < N) v4 = x4[j];
        else v4 = make_float4(0.f, 0.f, 0.f, 0.f);
        #pragma unroll
        for (int e = 0; e < 4; ++e) {
            int i = it * 4 + e;
            float v = (e == 0) ? v4.x : (e == 1) ? v4.y : (e == 2) ? v4.z : v4.w;
            vv[i] = v;
            int g = gi + e;
            if (g < N) {
                int off = (g >= bnd) ? 4 : 0;
                int f = fbin_of(v);
                int p = (f >= sB[off]) + (f >= sB[off + 1]) + (f >= sB[off + 2]) + (f >= sB[off + 3]);
                int sp = (off >> 2) * 5 + p;
                unsigned lr = atomicAdd(&hh[grp][sp], 1u);
                pk[i] = ((unsigned)sp << 10) | lr;
            } else pk[i] = 0xffffffffu;
        }
    }
    __syncthreads();
    if (t < 10) {
        unsigned run = 0;
        #pragma unroll
        for (int g = 0; g < 16; ++g) { unsigned c = hh[g][t]; hh[g][t] = run; run += c; }
        int s = s0 + (t >= 5);
        int p = (t >= 5) ? t - 5 : t;
        int rsv = 0;
        if (run > 0) rsv = (int)atomicAdd(&gcur[s * 8 + p], run);
        gb[t] = sst[s] + Bpos[s * 8 + p] + rsv;     // absolute base for this block's run
    }
    __syncthreads();
    #pragma unroll
    for (int i = 0; i < 8; ++i) {
        if (pk[i] == 0xffffffffu) continue;
        int sp = (int)(pk[i] >> 10);
        int lr = (int)(pk[i] & 1023u);
        part[gb[sp] + (int)hh[grp][sp] + lr] = vv[i];
    }
}

// ---- 3. per-(segment,window): contiguous slice -> LDS stage -> rank+diff ----
// s = bid % NSEG keeps all 5 blocks of a segment on one XCD (NSEG % 8 == 0).
__global__ void __launch_bounds__(BT)
k_seg(const float* __restrict__ part, const float* __restrict__ y,
      const int* __restrict__ seg_starts, const unsigned short* __restrict__ pfxg,
      const int* __restrict__ Bg, float* __restrict__ segSums) {
    __shared__ __align__(16) unsigned short pfx[NFB + 2];
    __shared__ unsigned cur[NFB / 4];
    __shared__ __align__(16) float win[WINCAP + 4];
    __shared__ float warr[16];
    int s = blockIdx.x % NSEG;
    int p = blockIdx.x / NSEG;
    int t = threadIdx.x;
    int st = seg_starts[s], en = seg_starts[s + 1];
    int n = en - st;
    if (n <= 0) return;
    const float* ys = y + st;
    const unsigned short* pp = pfxg + (size_t)s * PSTRIDE;
    ((uint4*)pfx)[t] = ((const uint4*)pp)[t];
    if (t == 0) pfx[NFB] = pp[NFB];
    __syncthreads();
    int Fa = Bg[s * 8 + p], Fb = Bg[s * 8 + p + 1];
    int w0 = (int)pfx[Fa], w1 = (int)pfx[Fb];
    int wsz = w1 - w0;
    int wA = Fa >> 2;
    int wB2 = (Fb > Fa) ? (((Fb - 1) >> 2) + 1) : wA;
    for (int k = wA + t; k < wB2; k += BT) cur[k] = 0u;
    __syncthreads();
    // stage: coalesced read of this window's contiguous partition slice
    const float* ps = part + st + w0;
    int head = min(wsz, (int)((4 - ((st + w0) & 3)) & 3));
    for (int k = t; k < head; k += BT) {
        float v = ps[k];
        int f = fbin_of(v);
        unsigned shf = (f & 3) * 8;
        unsigned old = atomicAdd(&cur[f >> 2], 1u << shf);
        win[(int)pfx[f] - w0 + (int)((old >> shf) & 0xFFu)] = v;
    }
    int nv = (wsz - head) >> 2;
    const float4* ps4 = (const float4*)(ps + head);
    for (int j = t; j < nv; j += BT) {
        float4 v4 = ps4[j];
        #pragma unroll
        for (int e = 0; e < 4; ++e) {
            float v = (e == 0) ? v4.x : (e == 1) ? v4.y : (e == 2) ? v4.z : v4.w;
            int f = fbin_of(v);
            unsigned shf = (f & 3) * 8;
            unsigned old = atomicAdd(&cur[f >> 2], 1u << shf);
            win[(int)pfx[f] - w0 + (int)((old >> shf) & 0xFFu)] = v;
        }
    }
    for (int k = head + nv * 4 + t; k < wsz; k += BT) {
        float v = ps[k];
        int f = fbin_of(v);
        unsigned shf = (f & 3) * 8;
        unsigned old = atomicAdd(&cur[f >> 2], 1u << shf);
        win[(int)pfx[f] - w0 + (int)((old >> shf) & 0xFFu)] = v;
    }
    if (t < 4) win[wsz + t] = __builtin_inff();   // pad for float4 over-read
    __syncthreads();
    // rank within fine bin (monotone bins: under-read strictly smaller ->
    // cancelled; over-read strictly larger / INF pad -> adds 0).
    float acc = 0.f;
    for (int q = w0 + t; q < w1; q += BT) {
        float v = win[q - w0];
        int f = fbin_of(v);
        int bs = (int)pfx[f], be = (int)pfx[f + 1];
        int ls = bs - w0, le = be - w0;
        int a = ls & ~3;
        int cnt = a - ls;
        for (int j = a; j < le; j += 4) {
            float4 qv = *(const float4*)&win[j];
            int jg = w0 + j;
            cnt += (qv.x < v) + ((qv.x == v) & (jg + 0 < q));
            cnt += (qv.y < v) + ((qv.y == v) & (jg + 1 < q));
            cnt += (qv.z < v) + ((qv.z == v) & (jg + 2 < q));
            cnt += (qv.w < v) + ((qv.w == v) & (jg + 3 < q));
        }
        acc += fabsf(v - ys[bs + cnt]);
    }
    for (int off = 32; off > 0; off >>= 1) acc += __shfl_xor(acc, off, 64);
    if ((t & 63) == 0) warr[t >> 6] = acc;
    __syncthreads();
    if (t == 0) {
        float tot = 0.f;
        #pragma unroll
        for (int j = 0; j < 16; ++j) tot += warr[j];
        if (tot != 0.f) atomicAdd(&segSums[s], tot);
    }
}

// ---- 4. finalize: mean over segments of sum/n * strength ----
__global__ void k_final(const float* __restrict__ segSums, const int* __restrict__ seg_starts,
                        float* __restrict__ out) {
    __shared__ float red[256];
    int t = threadIdx.x;
    float a = 0.f;
    for (int k = t; k < NSEG; k += 256) {
        float n = (float)(seg_starts[k + 1] - seg_starts[k]);
        a += segSums[k] / fmaxf(n, 1.0f);
    }
    red[t] = a;
    __syncthreads();
    for (int off = 128; off > 0; off >>= 1) {
        if (t < off) red[t] += red[t + off];
        __syncthreads();
    }
    if (t == 0) out[0] = red[0] * (1.0f / (float)NSEG) * STRENGTH;
}

extern "C" void kernel_launch(void* const* d_in, const int* in_sizes, int n_in,
                              void* d_out, int out_size, void* d_ws, size_t ws_size,
                              hipStream_t stream) {
    const float* x = (const float*)d_in[0];
    const float* y = (const float*)d_in[1];          // initial_sorted
    const int* seg = (const int*)d_in[2];            // segment_ids (sorted)
    int N = in_sizes[0];

    char* ws = (char*)d_ws;
    float* segSums    = (float*)ws;                          // 200 f32      @0
    int*   seg_starts = (int*)(ws + 800);                    // 201 i32      @800
    unsigned* gcur    = (unsigned*)(ws + 1616);              // 1600 u32     @1616
    int*   Bg         = (int*)(ws + 8016);                   // 1608 i32     @8016
    int*   Bpos       = (int*)(ws + 14448);                  // 1608 i32     @14448
    unsigned short* pfxg = (unsigned short*)(ws + 20880);    // 200*PSTRIDE u16
    float* part       = (float*)(ws + 20880 + (size_t)NSEG * PSTRIDE * 2 + 16);

    int nchunk = (N + PCH - 1) / PCH;

    k_bounds<<<512, 256, 0, stream>>>(seg, seg_starts, segSums, gcur, N);
    k_hist<<<NSEG, BT, 0, stream>>>(x, seg_starts, pfxg, Bg, Bpos);
    k_part<<<nchunk, 1024, 0, stream>>>(x, seg_starts, Bg, Bpos, gcur, part, N);
    k_seg<<<NSEG * SPLIT, BT, 0, stream>>>(part, y, seg_starts, pfxg, Bg, segSums);
    k_final<<<1, 256, 0, stream>>>(segSums, seg_starts, (float*)d_out);
}